// Round 6
// baseline (337.878 us; speedup 1.0000x reference)
//
#include <hip/hip_runtime.h>
#include <hip/hip_fp16.h>
#include <cstdint>
#include <cstddef>

#define T_DIM 5
#define F_DIM 8
#define Z_DIM 16
#define Y_DIM 96
#define X_DIM 96
#define NRAYS 32768
#define K_SAMP 128

// vol   [1][F=8][T=5][Z=16][Y=96][X=96]  strides: f:737280 t:147456 z:9216 y:96 x:1
// volT  [f][t][y][x][z0..15]             (z-contiguous, 23.6 MB) -- dead after conv
// fld   f32 [t][z][y][x]                 (2.95 MB)               -- overlaps dead volT
// cellp Cell[t][z][y][x] 16 B = 8 corner halves                  -- overlaps dead volT
// wR [tap][ci=(f*16+z_in)][z_out]: 27*128*16
// part[s][t][z][y][x], s = kt*4+fs (SK=12) or fs (SK=4)

struct __align__(16) Cell { __half2 h0, h1, h2, h3; };
// h0=(c000,c001) z0y0(x,x+1); h1=(c010,c011) z0y1; h2=(c100,c101) z1y0; h3=(c110,c111) z1y1

__global__ void prep_w_kernel(const float* __restrict__ w, const float* __restrict__ cb,
                              const float* __restrict__ dw,
                              float* __restrict__ wR, float* __restrict__ bR,
                              unsigned* loU, unsigned* hiU) {
    int i = blockIdx.x * 256 + threadIdx.x;
    if (i < 8) { loU[i] = 0x7F800000u; hiU[i] = 0u; }
    if (i < 27 * 128 * 16) {
        int tap = i >> 11;
        int r   = i & 2047;
        int ci  = r >> 4;
        int z   = r & 15;
        float s = 0.f;
        #pragma unroll
        for (int f = 0; f < 8; ++f)
            s += w[(size_t)((f * 16 + z) * 128 + ci) * 27 + tap] * dw[f];
        wR[i] = s;
    }
    if (i < 16) {
        float s = 0.f;
        #pragma unroll
        for (int f = 0; f < 8; ++f) s += cb[f * 16 + i] * dw[f];
        bR[i] = s;
    }
}

// volT[(((f*5+t)*96+y)*96+x)*16 + z] = vol[f][t][z][y][x]
__global__ __launch_bounds__(256) void transpose_vol_kernel(
        const float* __restrict__ xin, float* __restrict__ volT) {
    int gid = blockIdx.x * 256 + threadIdx.x;          // 0 .. 368639  (f,t,y,x)
    if (gid >= 8 * 5 * 96 * 96) return;
    int x = gid % 96;
    int r = gid / 96;
    int y = r % 96;
    int r2 = r / 96;
    int t = r2 % 5;
    int f = r2 / 5;
    const float* src = xin + (size_t)f * 737280 + t * 147456 + y * 96 + x;
    float v[16];
    #pragma unroll
    for (int z = 0; z < 16; ++z) v[z] = src[(size_t)z * 9216];
    float4* dst = (float4*)(volT + (size_t)gid * 16);
    dst[0] = make_float4(v[0], v[1], v[2], v[3]);
    dst[1] = make_float4(v[4], v[5], v[6], v[7]);
    dst[2] = make_float4(v[8], v[9], v[10], v[11]);
    dst[3] = make_float4(v[12], v[13], v[14], v[15]);
}

__global__ __launch_bounds__(256) void nearfar_kernel(
        const float* __restrict__ ro, const float* __restrict__ rd,
        float* __restrict__ nearA, float* __restrict__ farA,
        unsigned* loU, unsigned* hiU) {
    int gid = blockIdx.x * 256 + threadIdx.x;          // 0 .. T*NRAYS-1
    int t = gid / NRAYS;                               // block-uniform (128 blocks per t)
    const float* o = ro + (size_t)gid * 3;
    const float* d = rd + (size_t)gid * 3;
    float ox = o[0], oy = o[1], oz = o[2];
    float dx = d[0], dy = d[1], dz = d[2];
    float t1x = (0.f - ox) / dx, t2x = (1.f - ox) / dx;
    float t1y = (0.f - oy) / dy, t2y = (1.f - oy) / dy;
    float t1z = (0.f - oz) / dz, t2z = (1.f - oz) / dz;
    float nr = fmaxf(fmaxf(fminf(t1x, t2x), fminf(t1y, t2y)), fminf(t1z, t2z));
    float fr = fminf(fminf(fmaxf(t1x, t2x), fmaxf(t1y, t2y)), fmaxf(t1z, t2z));
    nr = fmaxf(nr, 0.01f);
    fr = fmaxf(fr, nr + 1e-6f);
    nearA[gid] = nr;
    farA[gid]  = fr;
    float slast = fmaf(0.9921875f, fr - nr, nr);       // starts[:,127]
    float mn = nr, mx = slast;
    #pragma unroll
    for (int off = 32; off > 0; off >>= 1) {
        mn = fminf(mn, __shfl_down(mn, off, 64));
        mx = fmaxf(mx, __shfl_down(mx, off, 64));
    }
    __shared__ float smn[4], smx[4];
    int w = threadIdx.x >> 6;
    if ((threadIdx.x & 63) == 0) { smn[w] = mn; smx[w] = mx; }
    __syncthreads();
    if (threadIdx.x == 0) {
        mn = fminf(fminf(smn[0], smn[1]), fminf(smn[2], smn[3]));
        mx = fmaxf(fmaxf(smx[0], smx[1]), fmaxf(smx[2], smx[3]));
        atomicMin(&loU[t], __float_as_uint(mn));   // positive floats: bit order == value order
        atomicMax(&hiU[t], __float_as_uint(mx));
    }
}

// Apply a 16-wide z_out weight row to two x-columns at once.
#define FMA16P(V0, V1, WPTR) { \
    float4 w0 = *(const float4*)(WPTR); \
    float4 w1 = *(const float4*)((WPTR) + 4); \
    float4 w2 = *(const float4*)((WPTR) + 8); \
    float4 w3 = *(const float4*)((WPTR) + 12); \
    acc0[0]  = fmaf(w0.x, V0, acc0[0]);  acc1[0]  = fmaf(w0.x, V1, acc1[0]); \
    acc0[1]  = fmaf(w0.y, V0, acc0[1]);  acc1[1]  = fmaf(w0.y, V1, acc1[1]); \
    acc0[2]  = fmaf(w0.z, V0, acc0[2]);  acc1[2]  = fmaf(w0.z, V1, acc1[2]); \
    acc0[3]  = fmaf(w0.w, V0, acc0[3]);  acc1[3]  = fmaf(w0.w, V1, acc1[3]); \
    acc0[4]  = fmaf(w1.x, V0, acc0[4]);  acc1[4]  = fmaf(w1.x, V1, acc1[4]); \
    acc0[5]  = fmaf(w1.y, V0, acc0[5]);  acc1[5]  = fmaf(w1.y, V1, acc1[5]); \
    acc0[6]  = fmaf(w1.z, V0, acc0[6]);  acc1[6]  = fmaf(w1.z, V1, acc1[6]); \
    acc0[7]  = fmaf(w1.w, V0, acc0[7]);  acc1[7]  = fmaf(w1.w, V1, acc1[7]); \
    acc0[8]  = fmaf(w2.x, V0, acc0[8]);  acc1[8]  = fmaf(w2.x, V1, acc1[8]); \
    acc0[9]  = fmaf(w2.y, V0, acc0[9]);  acc1[9]  = fmaf(w2.y, V1, acc1[9]); \
    acc0[10] = fmaf(w2.z, V0, acc0[10]); acc1[10] = fmaf(w2.z, V1, acc1[10]); \
    acc0[11] = fmaf(w2.w, V0, acc0[11]); acc1[11] = fmaf(w2.w, V1, acc1[11]); \
    acc0[12] = fmaf(w3.x, V0, acc0[12]); acc1[12] = fmaf(w3.x, V1, acc1[12]); \
    acc0[13] = fmaf(w3.y, V0, acc0[13]); acc1[13] = fmaf(w3.y, V1, acc1[13]); \
    acc0[14] = fmaf(w3.z, V0, acc0[14]); acc1[14] = fmaf(w3.z, V1, acc1[14]); \
    acc0[15] = fmaf(w3.w, V0, acc0[15]); acc1[15] = fmaf(w3.w, V1, acc1[15]); }

// KTS==1: kt fixed from blockIdx.z (SK=12). KTS==3: kt loop (SK=4 fallback).
// block (48,4): lane tx handles x = tx and x = tx+48 (both coalesced); y = bx*4+ty.
__global__ __launch_bounds__(192) void conv_kernel_t1(
        const float* __restrict__ volT, const float* __restrict__ wR,
        float* __restrict__ part, int KTS) {
    const int tx = threadIdx.x;                  // 0..47
    const int ty = threadIdx.y;                  // 0..3
    const int y  = blockIdx.x * 4 + ty;          // 0..95
    const int t  = blockIdx.y;                   // 0..4
    const int s  = blockIdx.z;                   // SK=12: kt*4+fs ; SK=4: fs
    const int fs = s & 3;
    const int kt_lo = (KTS == 1) ? (s >> 2)     : 0;
    const int kt_hi = (KTS == 1) ? (s >> 2) + 1 : 3;

    float acc0[16], acc1[16];
    #pragma unroll
    for (int z = 0; z < 16; ++z) { acc0[z] = 0.f; acc1[z] = 0.f; }

    for (int kt = kt_lo; kt < kt_hi; ++kt) {
        int tt = t + kt - 1;
        if (tt < 0 || tt >= T_DIM) continue;             // block-uniform
        for (int ky = 0; ky < 3; ++ky) {
            int yy = y + ky - 1;
            if (yy < 0 || yy >= Y_DIM) continue;         // wave-mostly-uniform
            for (int kx = 0; kx < 3; ++kx) {
                int xx0 = tx + kx - 1;                   // [-1, 48]  lower check only
                int xx1 = tx + 48 + kx - 1;              // [47, 96]  upper check only
                const int tap = (kt * 3 + ky) * 3 + kx;
                #pragma unroll
                for (int fi = 0; fi < 2; ++fi) {
                    const int f = fs * 2 + fi;
                    const float* rowp = volT +
                        ((((size_t)f * T_DIM + tt) * 96 + yy) * 96) * 16;
                    float4 a0, b0, c0, d0, a1, b1, c1, d1;
                    if (xx0 >= 0) {                      // zero-pad SAME conv
                        const float4* vp = (const float4*)(rowp + (size_t)xx0 * 16);
                        a0 = vp[0]; b0 = vp[1]; c0 = vp[2]; d0 = vp[3];
                    } else {
                        a0 = b0 = c0 = d0 = make_float4(0.f, 0.f, 0.f, 0.f);
                    }
                    if (xx1 < 96) {
                        const float4* vp = (const float4*)(rowp + (size_t)xx1 * 16);
                        a1 = vp[0]; b1 = vp[1]; c1 = vp[2]; d1 = vp[3];
                    } else {
                        a1 = b1 = c1 = d1 = make_float4(0.f, 0.f, 0.f, 0.f);
                    }
                    const float* wp = wR + (size_t)(tap * 128 + f * 16) * 16;
                    FMA16P(a0.x, a1.x, wp);        FMA16P(a0.y, a1.y, wp + 16);
                    FMA16P(a0.z, a1.z, wp + 32);   FMA16P(a0.w, a1.w, wp + 48);
                    FMA16P(b0.x, b1.x, wp + 64);   FMA16P(b0.y, b1.y, wp + 80);
                    FMA16P(b0.z, b1.z, wp + 96);   FMA16P(b0.w, b1.w, wp + 112);
                    FMA16P(c0.x, c1.x, wp + 128);  FMA16P(c0.y, c1.y, wp + 144);
                    FMA16P(c0.z, c1.z, wp + 160);  FMA16P(c0.w, c1.w, wp + 176);
                    FMA16P(d0.x, d1.x, wp + 192);  FMA16P(d0.y, d1.y, wp + 208);
                    FMA16P(d0.z, d1.z, wp + 224);  FMA16P(d0.w, d1.w, wp + 240);
                }
            }
        }
    }
    float* po = part + (size_t)s * 737280;
    #pragma unroll
    for (int z = 0; z < 16; ++z) {
        float* row = po + (((size_t)t * Z_DIM + z) * Y_DIM + y) * X_DIM;
        row[tx]      = acc0[z];
        row[tx + 48] = acc1[z];
    }
}

// fld = sum of SK partials + bias[z]. 184320 float4 groups.
__global__ __launch_bounds__(256) void combine_kernel(
        const float* __restrict__ part, const float* __restrict__ bR,
        float* __restrict__ fld, int SK) {
    int i = blockIdx.x * 256 + threadIdx.x;
    if (i >= 184320) return;
    int z = (i / 2304) & 15;
    float b = bR[z];
    float4 r = make_float4(b, b, b, b);
    const float4* p = (const float4*)part;
    for (int s = 0; s < SK; ++s) {
        float4 a = p[(size_t)s * 184320 + i];
        r.x += a.x; r.y += a.y; r.z += a.z; r.w += a.w;
    }
    ((float4*)fld)[i] = r;
}

// cellp[t][z][y][x] = 8 fp16 corners of cell (z..z+1, y..y+1, x..x+1), clamped at edges.
__global__ __launch_bounds__(256) void pack_kernel(
        const float* __restrict__ fld, Cell* __restrict__ cellp) {
    int i = blockIdx.x * 256 + threadIdx.x;
    if (i >= 737280) return;
    int x = i % 96;
    int r = i / 96;
    int y = r % 96;
    int r2 = r / 96;
    int z = r2 % 16;
    int t = r2 / 16;
    const float* ft = fld + (size_t)t * 147456;
    int xp = min(x + 1, 95);
    int yr0 = y * 96, yr1 = min(y + 1, 95) * 96;
    int zr0 = z * 9216, zr1 = min(z + 1, 15) * 9216;
    float c000 = ft[zr0 + yr0 + x], c001 = ft[zr0 + yr0 + xp];
    float c010 = ft[zr0 + yr1 + x], c011 = ft[zr0 + yr1 + xp];
    float c100 = ft[zr1 + yr0 + x], c101 = ft[zr1 + yr0 + xp];
    float c110 = ft[zr1 + yr1 + x], c111 = ft[zr1 + yr1 + xp];
    Cell cl;
    cl.h0 = __floats2half2_rn(c000, c001);
    cl.h1 = __floats2half2_rn(c010, c011);
    cl.h2 = __floats2half2_rn(c100, c101);
    cl.h3 = __floats2half2_rn(c110, c111);
    cellp[i] = cl;
}

// 4 lanes per ray, 32 samples each. XCD-affinity block remap: blocks dispatch b%8 -> XCD,
// so XCD 0..4 serve one t each (2.36 MB, L2-resident); XCD 5..7 share the remainder.
__global__ __launch_bounds__(256) void render_kernel(
        const float* __restrict__ ro, const float* __restrict__ rd,
        const Cell* __restrict__ cellp,
        const float* __restrict__ nearA, const float* __restrict__ farA,
        const unsigned* __restrict__ loU, const unsigned* __restrict__ hiU,
        const float* __restrict__ dens_b, float* __restrict__ out) {
    int b = blockIdx.x;                 // 0..2559
    int b7 = b & 7, bhi = b >> 3;       // bhi 0..319
    int t, seg;
    if (b7 < 5) { t = b7; seg = bhi; }
    else { int j = (b7 - 5) * 320 + bhi; t = j / 192; seg = 320 + j % 192; }
    int c = threadIdx.x & 3;
    int ray = t * NRAYS + seg * 64 + (threadIdx.x >> 2);

    const float* o = ro + (size_t)ray * 3;
    const float* d = rd + (size_t)ray * 3;
    float ox = o[0], oy = o[1], oz = o[2];
    float dx = d[0], dy = d[1], dz = d[2];
    float nr = nearA[ray], fr = farA[ray];
    float span = fr - nr;
    const Cell* vt = cellp + (size_t)t * 147456;
    float db = dens_b[0];

    float step = span * 0.0078125f;
    float s  = fmaf((float)(c * 32), step, nr);
    float mid = s + 0.5f * step;
    float px = fmaf(dx, mid, ox);
    float py = fmaf(dy, mid, oy);
    float pz = fmaf(dz, mid, oz);
    float ddx = dx * step, ddy = dy * step, ddz = dz * step;

    float num = 0.f, den = 0.f, A = 0.f;
    float trans = 1.f;
    int pidx = -1;
    float2 f00 = {0.f, 0.f}, f01 = {0.f, 0.f}, f10 = {0.f, 0.f}, f11 = {0.f, 0.f};
    for (int kk = 0; kk < 32; ++kk) {
        float gx = fminf(fmaxf(px, 0.f), 1.f) * 95.f;
        float gy = fminf(fmaxf(py, 0.f), 1.f) * 95.f;
        float gz = fminf(fmaxf(pz, 0.f), 1.f) * 15.f;
        int x0 = min((int)gx, 94), y0 = min((int)gy, 94), z0 = min((int)gz, 14);
        float fx = gx - (float)x0, fy = gy - (float)y0, fz = gz - (float)z0;

        int idx = z0 * 9216 + y0 * 96 + x0;
        if (idx != pidx) {                    // exec-masked reload; ~1 dwordx4 per new cell
            pidx = idx;
            Cell cl = vt[idx];
            f00 = __half22float2(cl.h0);
            f01 = __half22float2(cl.h1);
            f10 = __half22float2(cl.h2);
            f11 = __half22float2(cl.h3);
        }

        float v00 = f00.x + fx * (f00.y - f00.x);
        float v01 = f01.x + fx * (f01.y - f01.x);
        float v10 = f10.x + fx * (f10.y - f10.x);
        float v11 = f11.x + fx * (f11.y - f11.x);
        float v0  = v00 + fy * (v01 - v00);
        float v1  = v10 + fy * (v11 - v10);
        float pre = v0 + fz * (v1 - v0) + db;

        float u = __expf(-fabsf(pre));
        float dens = fmaxf(pre, 0.f) + __logf(1.f + u);   // softplus
        float dd = dens * step;
        float ex = __expf(-dd);
        float w = (1.f - ex) * trans;
        num = fmaf(w, s, num);
        den += w;
        trans *= ex;
        A += dd;
        s += step; px += ddx; py += ddy; pz += ddz;
    }
    // prefix transmittance across the 4 chunks of this ray
    int lane = threadIdx.x & 63;
    int q = lane & ~3;
    float A0 = __shfl(A, q,     64);
    float A1 = __shfl(A, q + 1, 64);
    float A2 = __shfl(A, q + 2, 64);
    float P = 0.f;
    if (c > 0) P += A0;
    if (c > 1) P += A1;
    if (c > 2) P += A2;
    float sc = __expf(-P);
    float numc = num * sc;
    float denc = den * sc;
    numc += __shfl_xor(numc, 1, 64);
    numc += __shfl_xor(numc, 2, 64);
    denc += __shfl_xor(denc, 1, 64);
    denc += __shfl_xor(denc, 2, 64);
    if (c == 0) {
        float depth = numc / (denc + 1e-10f);
        float lo = __uint_as_float(loU[t]);
        float hi = __uint_as_float(hiU[t]);
        depth = fminf(fmaxf(depth, lo), hi);
        out[ray] = depth;
    }
}

extern "C" void kernel_launch(void* const* d_in, const int* in_sizes, int n_in,
                              void* d_out, int out_size, void* d_ws, size_t ws_size,
                              hipStream_t stream) {
    const float* vol = (const float*)d_in[0];   // [1,8,5,16,96,96]
    const float* ro  = (const float*)d_in[1];   // [5,32768,3]
    const float* rd  = (const float*)d_in[2];   // [5,32768,3]
    const float* cw  = (const float*)d_in[3];   // [128,128,3,3,3]
    const float* cb  = (const float*)d_in[4];   // [128]
    const float* dw  = (const float*)d_in[5];   // [8,1]
    const float* dbp = (const float*)d_in[6];   // [1]
    float* out = (float*)d_out;                 // [5,32768,1] f32

    // Region A (5,898,240 floats): volT during conv; fld (737,280) + cellp (2,949,120)
    // after conv (volT dead). part follows; misc at the end.
    const size_t A_FLOATS = 5898240;
    const size_t misc = 55296 + 32 + 163840 + 163840 + 16 + 64;
    const int SK = (ws_size >= (A_FLOATS + 12ull * 737280 + misc) * 4) ? 12 : 4;

    float* ws      = (float*)d_ws;
    float* volT    = ws;                          // A: [0 .. 5,898,240)
    float* fld     = ws;                          // A: [0 .. 737,280)  (after conv)
    Cell*  cellp   = (Cell*)(ws + 737280);        // A: [737,280 .. 3,686,400)
    float* part    = ws + A_FLOATS;               // SK * 737,280
    float* wR      = part + (size_t)SK * 737280;  // 55,296
    float* bR      = wR + 55296;                  // 16 (+pad 32)
    float* nearA   = bR + 32;                     // 163,840
    float* farA    = nearA + 163840;              // 163,840
    unsigned* loU  = (unsigned*)(farA + 163840);  // 8
    unsigned* hiU  = loU + 8;                     // 8

    hipLaunchKernelGGL(prep_w_kernel, dim3(216), dim3(256), 0, stream,
                       cw, cb, dw, wR, bR, loU, hiU);
    hipLaunchKernelGGL(transpose_vol_kernel, dim3(1440), dim3(256), 0, stream, vol, volT);
    hipLaunchKernelGGL(nearfar_kernel, dim3(640), dim3(256), 0, stream,
                       ro, rd, nearA, farA, loU, hiU);
    if (SK == 12) {
        hipLaunchKernelGGL(conv_kernel_t1, dim3(24, 5, 12), dim3(48, 4), 0, stream,
                           volT, wR, part, 1);
    } else {
        hipLaunchKernelGGL(conv_kernel_t1, dim3(24, 5, 4), dim3(48, 4), 0, stream,
                           volT, wR, part, 3);
    }
    hipLaunchKernelGGL(combine_kernel, dim3(720), dim3(256), 0, stream, part, bR, fld, SK);
    hipLaunchKernelGGL(pack_kernel, dim3(2880), dim3(256), 0, stream, fld, cellp);
    hipLaunchKernelGGL(render_kernel, dim3(2560), dim3(256), 0, stream,
                       ro, rd, cellp, nearA, farA, loU, hiU, dbp, out);
}

// Round 7
// 236.169 us; speedup vs baseline: 1.4307x; 1.4307x over previous
//
#include <hip/hip_runtime.h>
#include <hip/hip_fp16.h>
#include <cstdint>
#include <cstddef>

#define T_DIM 5
#define F_DIM 8
#define Z_DIM 16
#define Y_DIM 96
#define X_DIM 96
#define NRAYS 32768
#define K_SAMP 128

// vol   [1][F=8][T=5][Z=16][Y=96][X=96]  strides: f:737280 t:147456 z:9216 y:96 x:1
// volT  [f][t][y][x][z0..15]             (z-contiguous, 23.6 MB) -- dead after conv
// fld   f32 [t][z][y][x]                 (2.95 MB)               -- overlaps dead volT
// cellp Cell[t][z][y][x] 16 B = 8 corner halves                  -- overlaps dead volT
// wR [tap][ci=(f*16+z_in)][z_out]: 27*128*16
// part[s][t][z][y][x], s = kt*4+fs (SK=12) or fs (SK=4)

struct __align__(16) Cell { __half2 h0, h1, h2, h3; };
// h0=(c000,c001) z0y0(x,x+1); h1=(c010,c011) z0y1; h2=(c100,c101) z1y0; h3=(c110,c111) z1y1

__global__ void prep_w_kernel(const float* __restrict__ w, const float* __restrict__ cb,
                              const float* __restrict__ dw,
                              float* __restrict__ wR, float* __restrict__ bR,
                              unsigned* loU, unsigned* hiU) {
    int i = blockIdx.x * 256 + threadIdx.x;
    if (i < 8) { loU[i] = 0x7F800000u; hiU[i] = 0u; }
    if (i < 27 * 128 * 16) {
        int tap = i >> 11;
        int r   = i & 2047;
        int ci  = r >> 4;
        int z   = r & 15;
        float s = 0.f;
        #pragma unroll
        for (int f = 0; f < 8; ++f)
            s += w[(size_t)((f * 16 + z) * 128 + ci) * 27 + tap] * dw[f];
        wR[i] = s;
    }
    if (i < 16) {
        float s = 0.f;
        #pragma unroll
        for (int f = 0; f < 8; ++f) s += cb[f * 16 + i] * dw[f];
        bR[i] = s;
    }
}

// volT[(((f*5+t)*96+y)*96+x)*16 + z] = vol[f][t][z][y][x]
__global__ __launch_bounds__(256) void transpose_vol_kernel(
        const float* __restrict__ xin, float* __restrict__ volT) {
    int gid = blockIdx.x * 256 + threadIdx.x;          // 0 .. 368639  (f,t,y,x)
    if (gid >= 8 * 5 * 96 * 96) return;
    int x = gid % 96;
    int r = gid / 96;
    int y = r % 96;
    int r2 = r / 96;
    int t = r2 % 5;
    int f = r2 / 5;
    const float* src = xin + (size_t)f * 737280 + t * 147456 + y * 96 + x;
    float v[16];
    #pragma unroll
    for (int z = 0; z < 16; ++z) v[z] = src[(size_t)z * 9216];
    float4* dst = (float4*)(volT + (size_t)gid * 16);
    dst[0] = make_float4(v[0], v[1], v[2], v[3]);
    dst[1] = make_float4(v[4], v[5], v[6], v[7]);
    dst[2] = make_float4(v[8], v[9], v[10], v[11]);
    dst[3] = make_float4(v[12], v[13], v[14], v[15]);
}

__global__ __launch_bounds__(256) void nearfar_kernel(
        const float* __restrict__ ro, const float* __restrict__ rd,
        float* __restrict__ nearA, float* __restrict__ farA,
        unsigned* loU, unsigned* hiU) {
    int gid = blockIdx.x * 256 + threadIdx.x;          // 0 .. T*NRAYS-1
    int t = gid / NRAYS;                               // block-uniform (128 blocks per t)
    const float* o = ro + (size_t)gid * 3;
    const float* d = rd + (size_t)gid * 3;
    float ox = o[0], oy = o[1], oz = o[2];
    float dx = d[0], dy = d[1], dz = d[2];
    float t1x = (0.f - ox) / dx, t2x = (1.f - ox) / dx;
    float t1y = (0.f - oy) / dy, t2y = (1.f - oy) / dy;
    float t1z = (0.f - oz) / dz, t2z = (1.f - oz) / dz;
    float nr = fmaxf(fmaxf(fminf(t1x, t2x), fminf(t1y, t2y)), fminf(t1z, t2z));
    float fr = fminf(fminf(fmaxf(t1x, t2x), fmaxf(t1y, t2y)), fmaxf(t1z, t2z));
    nr = fmaxf(nr, 0.01f);
    fr = fmaxf(fr, nr + 1e-6f);
    nearA[gid] = nr;
    farA[gid]  = fr;
    float slast = fmaf(0.9921875f, fr - nr, nr);       // starts[:,127]
    float mn = nr, mx = slast;
    #pragma unroll
    for (int off = 32; off > 0; off >>= 1) {
        mn = fminf(mn, __shfl_down(mn, off, 64));
        mx = fmaxf(mx, __shfl_down(mx, off, 64));
    }
    __shared__ float smn[4], smx[4];
    int w = threadIdx.x >> 6;
    if ((threadIdx.x & 63) == 0) { smn[w] = mn; smx[w] = mx; }
    __syncthreads();
    if (threadIdx.x == 0) {
        mn = fminf(fminf(smn[0], smn[1]), fminf(smn[2], smn[3]));
        mx = fmaxf(fmaxf(smx[0], smx[1]), fmaxf(smx[2], smx[3]));
        atomicMin(&loU[t], __float_as_uint(mn));   // positive floats: bit order == value order
        atomicMax(&hiU[t], __float_as_uint(mx));
    }
}

#define FMA16(VV, WPTR) { \
    float4 w0 = *(const float4*)(WPTR); \
    float4 w1 = *(const float4*)((WPTR) + 4); \
    float4 w2 = *(const float4*)((WPTR) + 8); \
    float4 w3 = *(const float4*)((WPTR) + 12); \
    acc[0]  = fmaf(w0.x, VV, acc[0]);  acc[1]  = fmaf(w0.y, VV, acc[1]); \
    acc[2]  = fmaf(w0.z, VV, acc[2]);  acc[3]  = fmaf(w0.w, VV, acc[3]); \
    acc[4]  = fmaf(w1.x, VV, acc[4]);  acc[5]  = fmaf(w1.y, VV, acc[5]); \
    acc[6]  = fmaf(w1.z, VV, acc[6]);  acc[7]  = fmaf(w1.w, VV, acc[7]); \
    acc[8]  = fmaf(w2.x, VV, acc[8]);  acc[9]  = fmaf(w2.y, VV, acc[9]); \
    acc[10] = fmaf(w2.z, VV, acc[10]); acc[11] = fmaf(w2.w, VV, acc[11]); \
    acc[12] = fmaf(w3.x, VV, acc[12]); acc[13] = fmaf(w3.y, VV, acc[13]); \
    acc[14] = fmaf(w3.z, VV, acc[14]); acc[15] = fmaf(w3.w, VV, acc[15]); }

// R4's proven conv. KTS==1: kt fixed from blockIdx.z (SK=12). KTS==3: kt loop (SK=4).
template<int KTS>
__global__ __launch_bounds__(192) void conv_kernel(
        const float* __restrict__ volT, const float* __restrict__ wR,
        float* __restrict__ part) {
    const int x  = threadIdx.x;                  // 0..95
    const int ty = threadIdx.y;                  // 0..1
    const int y  = blockIdx.x * 2 + ty;          // 0..95
    const int t  = blockIdx.y;                   // 0..4
    const int s  = blockIdx.z;                   // SK=12: kt*4+fs ; SK=4: fs
    const int fs = s & 3;
    const int kt_lo = (KTS == 1) ? (s >> 2)     : 0;
    const int kt_hi = (KTS == 1) ? (s >> 2) + 1 : 3;

    float acc[16];
    #pragma unroll
    for (int z = 0; z < 16; ++z) acc[z] = 0.f;

    for (int kt = kt_lo; kt < kt_hi; ++kt) {
        int tt = t + kt - 1;
        if (tt < 0 || tt >= T_DIM) continue;             // block-uniform
        for (int ky = 0; ky < 3; ++ky) {
            int yy = y + ky - 1;
            if (yy < 0 || yy >= Y_DIM) continue;
            for (int kx = 0; kx < 3; ++kx) {
                int xx = x + kx - 1;
                if (xx < 0 || xx >= X_DIM) continue;     // divergent only at lanes 0/95
                const int tap = (kt * 3 + ky) * 3 + kx;
                #pragma unroll
                for (int fi = 0; fi < 2; ++fi) {
                    const int f = fs * 2 + fi;
                    const float4* vp = (const float4*)(volT +
                        ((((size_t)f * T_DIM + tt) * 96 + yy) * 96 + xx) * 16);
                    float4 va = vp[0], vb = vp[1], vc = vp[2], vd = vp[3];
                    const float* wp = wR + (size_t)(tap * 128 + f * 16) * 16;
                    FMA16(va.x, wp);        FMA16(va.y, wp + 16);
                    FMA16(va.z, wp + 32);   FMA16(va.w, wp + 48);
                    FMA16(vb.x, wp + 64);   FMA16(vb.y, wp + 80);
                    FMA16(vb.z, wp + 96);   FMA16(vb.w, wp + 112);
                    FMA16(vc.x, wp + 128);  FMA16(vc.y, wp + 144);
                    FMA16(vc.z, wp + 160);  FMA16(vc.w, wp + 176);
                    FMA16(vd.x, wp + 192);  FMA16(vd.y, wp + 208);
                    FMA16(vd.z, wp + 224);  FMA16(vd.w, wp + 240);
                }
            }
        }
    }
    float* po = part + (size_t)s * 737280;
    #pragma unroll
    for (int z = 0; z < 16; ++z)
        po[(((size_t)t * Z_DIM + z) * Y_DIM + y) * X_DIM + x] = acc[z];
}

// fld = sum of SK partials + bias[z]. 184320 float4 groups.
__global__ __launch_bounds__(256) void combine_kernel(
        const float* __restrict__ part, const float* __restrict__ bR,
        float* __restrict__ fld, int SK) {
    int i = blockIdx.x * 256 + threadIdx.x;
    if (i >= 184320) return;
    int z = (i / 2304) & 15;
    float b = bR[z];
    float4 r = make_float4(b, b, b, b);
    const float4* p = (const float4*)part;
    for (int s = 0; s < SK; ++s) {
        float4 a = p[(size_t)s * 184320 + i];
        r.x += a.x; r.y += a.y; r.z += a.z; r.w += a.w;
    }
    ((float4*)fld)[i] = r;
}

// cellp[t][z][y][x] = 8 fp16 corners of cell (z..z+1, y..y+1, x..x+1), clamped at edges.
__global__ __launch_bounds__(256) void pack_kernel(
        const float* __restrict__ fld, Cell* __restrict__ cellp) {
    int i = blockIdx.x * 256 + threadIdx.x;
    if (i >= 737280) return;
    int x = i % 96;
    int r = i / 96;
    int y = r % 96;
    int r2 = r / 96;
    int z = r2 % 16;
    int t = r2 / 16;
    const float* ft = fld + (size_t)t * 147456;
    int xp = min(x + 1, 95);
    int yr0 = y * 96, yr1 = min(y + 1, 95) * 96;
    int zr0 = z * 9216, zr1 = min(z + 1, 15) * 9216;
    float c000 = ft[zr0 + yr0 + x], c001 = ft[zr0 + yr0 + xp];
    float c010 = ft[zr0 + yr1 + x], c011 = ft[zr0 + yr1 + xp];
    float c100 = ft[zr1 + yr0 + x], c101 = ft[zr1 + yr0 + xp];
    float c110 = ft[zr1 + yr1 + x], c111 = ft[zr1 + yr1 + xp];
    Cell cl;
    cl.h0 = __floats2half2_rn(c000, c001);
    cl.h1 = __floats2half2_rn(c010, c011);
    cl.h2 = __floats2half2_rn(c100, c101);
    cl.h3 = __floats2half2_rn(c110, c111);
    cellp[i] = cl;
}

// 4 lanes per ray, 32 samples each, processed in batches of 4 with deduped
// overlapped Cell loads (latency/4). XCD-affinity block remap as in R4.
__global__ __launch_bounds__(256) void render_kernel(
        const float* __restrict__ ro, const float* __restrict__ rd,
        const Cell* __restrict__ cellp,
        const float* __restrict__ nearA, const float* __restrict__ farA,
        const unsigned* __restrict__ loU, const unsigned* __restrict__ hiU,
        const float* __restrict__ dens_b, float* __restrict__ out) {
    int b = blockIdx.x;                 // 0..2559
    int b7 = b & 7, bhi = b >> 3;       // bhi 0..319
    int t, seg;
    if (b7 < 5) { t = b7; seg = bhi; }
    else { int j = (b7 - 5) * 320 + bhi; t = j / 192; seg = 320 + j % 192; }
    int c = threadIdx.x & 3;
    int ray = t * NRAYS + seg * 64 + (threadIdx.x >> 2);

    const float* o = ro + (size_t)ray * 3;
    const float* d = rd + (size_t)ray * 3;
    float ox = o[0], oy = o[1], oz = o[2];
    float dx = d[0], dy = d[1], dz = d[2];
    float nr = nearA[ray], fr = farA[ray];
    float span = fr - nr;
    const Cell* vt = cellp + (size_t)t * 147456;
    float db = dens_b[0];

    float step = span * 0.0078125f;
    float s  = fmaf((float)(c * 32), step, nr);
    float mid = s + 0.5f * step;
    float px = fmaf(dx, mid, ox);
    float py = fmaf(dy, mid, oy);
    float pz = fmaf(dz, mid, oz);
    float ddx = dx * step, ddy = dy * step, ddz = dz * step;

    float num = 0.f, den = 0.f, A = 0.f;
    float trans = 1.f;
    int pidx = -1;
    float2 f00 = {0.f, 0.f}, f01 = {0.f, 0.f}, f10 = {0.f, 0.f}, f11 = {0.f, 0.f};

    for (int bb = 0; bb < 8; ++bb) {
        // phase 1: 4 sample addresses + fractions (pure arithmetic)
        int   idxv[4];
        float fxv[4], fyv[4], fzv[4];
        #pragma unroll
        for (int j = 0; j < 4; ++j) {
            float gx = fminf(fmaxf(px, 0.f), 1.f) * 95.f;
            float gy = fminf(fmaxf(py, 0.f), 1.f) * 95.f;
            float gz = fminf(fmaxf(pz, 0.f), 1.f) * 15.f;
            int x0 = min((int)gx, 94), y0 = min((int)gy, 94), z0 = min((int)gz, 14);
            fxv[j] = gx - (float)x0; fyv[j] = gy - (float)y0; fzv[j] = gz - (float)z0;
            idxv[j] = z0 * 9216 + y0 * 96 + x0;
            px += ddx; py += ddy; pz += ddz;
        }
        // phase 2: deduped loads, independent dest regs -> overlapped in flight
        bool n0 = idxv[0] != pidx;
        bool n1 = idxv[1] != idxv[0];
        bool n2 = idxv[2] != idxv[1];
        bool n3 = idxv[3] != idxv[2];
        Cell c0, c1, c2, c3;
        if (n0) c0 = vt[idxv[0]];
        if (n1) c1 = vt[idxv[1]];
        if (n2) c2 = vt[idxv[2]];
        if (n3) c3 = vt[idxv[3]];
        pidx = idxv[3];
        // phase 3: sequential accumulation
        #define PROC(J, CJ, NJ) { \
            if (NJ) { \
                f00 = __half22float2(CJ.h0); f01 = __half22float2(CJ.h1); \
                f10 = __half22float2(CJ.h2); f11 = __half22float2(CJ.h3); \
            } \
            float fx = fxv[J], fy = fyv[J], fz = fzv[J]; \
            float v00 = f00.x + fx * (f00.y - f00.x); \
            float v01 = f01.x + fx * (f01.y - f01.x); \
            float v10 = f10.x + fx * (f10.y - f10.x); \
            float v11 = f11.x + fx * (f11.y - f11.x); \
            float v0  = v00 + fy * (v01 - v00); \
            float v1  = v10 + fy * (v11 - v10); \
            float pre = v0 + fz * (v1 - v0) + db; \
            float u = __expf(-fabsf(pre)); \
            float dens = fmaxf(pre, 0.f) + __logf(1.f + u); \
            float dd = dens * step; \
            float ex = __expf(-dd); \
            float w = (1.f - ex) * trans; \
            num = fmaf(w, s, num); \
            den += w; \
            trans *= ex; \
            A += dd; \
            s += step; }
        PROC(0, c0, n0) PROC(1, c1, n1) PROC(2, c2, n2) PROC(3, c3, n3)
        #undef PROC
    }
    // prefix transmittance across the 4 chunks of this ray
    int lane = threadIdx.x & 63;
    int q = lane & ~3;
    float A0 = __shfl(A, q,     64);
    float A1 = __shfl(A, q + 1, 64);
    float A2 = __shfl(A, q + 2, 64);
    float P = 0.f;
    if (c > 0) P += A0;
    if (c > 1) P += A1;
    if (c > 2) P += A2;
    float sc = __expf(-P);
    float numc = num * sc;
    float denc = den * sc;
    numc += __shfl_xor(numc, 1, 64);
    numc += __shfl_xor(numc, 2, 64);
    denc += __shfl_xor(denc, 1, 64);
    denc += __shfl_xor(denc, 2, 64);
    if (c == 0) {
        float depth = numc / (denc + 1e-10f);
        float lo = __uint_as_float(loU[t]);
        float hi = __uint_as_float(hiU[t]);
        depth = fminf(fmaxf(depth, lo), hi);
        out[ray] = depth;
    }
}

extern "C" void kernel_launch(void* const* d_in, const int* in_sizes, int n_in,
                              void* d_out, int out_size, void* d_ws, size_t ws_size,
                              hipStream_t stream) {
    const float* vol = (const float*)d_in[0];   // [1,8,5,16,96,96]
    const float* ro  = (const float*)d_in[1];   // [5,32768,3]
    const float* rd  = (const float*)d_in[2];   // [5,32768,3]
    const float* cw  = (const float*)d_in[3];   // [128,128,3,3,3]
    const float* cb  = (const float*)d_in[4];   // [128]
    const float* dw  = (const float*)d_in[5];   // [8,1]
    const float* dbp = (const float*)d_in[6];   // [1]
    float* out = (float*)d_out;                 // [5,32768,1] f32

    // Region A (5,898,240 floats): volT during conv; fld (737,280) + cellp (2,949,120)
    // after conv (volT dead). part follows; misc at the end.
    const size_t A_FLOATS = 5898240;
    const size_t misc = 55296 + 32 + 163840 + 163840 + 16 + 64;
    const int SK = (ws_size >= (A_FLOATS + 12ull * 737280 + misc) * 4) ? 12 : 4;

    float* ws      = (float*)d_ws;
    float* volT    = ws;                          // A: [0 .. 5,898,240)
    float* fld     = ws;                          // A: [0 .. 737,280)  (after conv)
    Cell*  cellp   = (Cell*)(ws + 737280);        // A: [737,280 .. 3,686,400)
    float* part    = ws + A_FLOATS;               // SK * 737,280
    float* wR      = part + (size_t)SK * 737280;  // 55,296
    float* bR      = wR + 55296;                  // 16 (+pad 32)
    float* nearA   = bR + 32;                     // 163,840
    float* farA    = nearA + 163840;              // 163,840
    unsigned* loU  = (unsigned*)(farA + 163840);  // 8
    unsigned* hiU  = loU + 8;                     // 8

    hipLaunchKernelGGL(prep_w_kernel, dim3(216), dim3(256), 0, stream,
                       cw, cb, dw, wR, bR, loU, hiU);
    hipLaunchKernelGGL(transpose_vol_kernel, dim3(1440), dim3(256), 0, stream, vol, volT);
    hipLaunchKernelGGL(nearfar_kernel, dim3(640), dim3(256), 0, stream,
                       ro, rd, nearA, farA, loU, hiU);
    if (SK == 12) {
        hipLaunchKernelGGL(conv_kernel<1>, dim3(48, 5, 12), dim3(96, 2), 0, stream,
                           volT, wR, part);
    } else {
        hipLaunchKernelGGL(conv_kernel<3>, dim3(48, 5, 4), dim3(96, 2), 0, stream,
                           volT, wR, part);
    }
    hipLaunchKernelGGL(combine_kernel, dim3(720), dim3(256), 0, stream, part, bR, fld, SK);
    hipLaunchKernelGGL(pack_kernel, dim3(2880), dim3(256), 0, stream, fld, cellp);
    hipLaunchKernelGGL(render_kernel, dim3(2560), dim3(256), 0, stream,
                       ro, rd, cellp, nearA, farA, loU, hiU, dbp, out);
}